// Round 7
// baseline (108.614 us; speedup 1.0000x reference)
//
#include <hip/hip_runtime.h>
#include <hip/hip_bf16.h>
#include <stdint.h>

// Fused causal attention head, MI355X (gfx950). Round 11.
// attn v4 "folded pair": every block owns BOTH q-row-blocks m and 63-m
// (sequentially) at one split sp -> ntiles uniform (16..18) across ALL 512
// blocks. 512 x 512thr = 2 blocks/CU, 16 waves/CU with zero tail (v3's tail
// -- the m=63 block running its last tiles nearly alone -- is eliminated).
// Inner loop identical to v3 (qg x sh waves, dbuf K/V, one barrier/tile,
// prefetch-after-barrier, cvt_pk + permlane P-transform). Seam: merge
// phase-A s-halves via dedicated LDS scratch, write partials, reset, reload
// Q for mB. Blocks with nB==0 zero-fill the phase-B slot; combine unchanged.
// wprep/proj/combine identical to R10.

#define EMBED 384
#define HEAD  64
#define NB    4
#define NT    4096
#define NROWS (NB * NT) // 16384
#define NSPLIT 4

#define SCALE_Q 0.18033688011112042f // 0.125 * log2(e), folded into Q

typedef short bf16x8 __attribute__((ext_vector_type(8)));
typedef float f32x4  __attribute__((ext_vector_type(4)));

__device__ __forceinline__ unsigned short bfround(float f) {
    union { float f; unsigned u; } v; v.f = f;
    return (unsigned short)((v.u + 0x8000u) >> 16);
}
__device__ __forceinline__ unsigned packbf(float lo, float hi) {
    union { float f; unsigned u; } a, b; a.f = lo; b.f = hi;
    return ((a.u + 0x8000u) >> 16) | ((b.u + 0x8000u) & 0xFFFF0000u);
}
__device__ __forceinline__ unsigned cvtpk(float lo, float hi) {
    unsigned r;
    asm("v_cvt_pk_bf16_f32 %0, %1, %2" : "=v"(r) : "v"(lo), "v"(hi));
    return r;
}

// gfx950 lane-group swaps. swap32: A_upper32 <-> B_lower32.
// swap16: A rows 1,3 (16-lane rows) <-> B rows 0,2.
__device__ __forceinline__ void pl_swap32(unsigned& a, unsigned& b) {
    asm("v_permlane32_swap_b32 %0, %1" : "+v"(a), "+v"(b));
}
__device__ __forceinline__ void pl_swap16(unsigned& a, unsigned& b) {
    asm("v_permlane16_swap_b32 %0, %1" : "+v"(a), "+v"(b));
}

// ---------------------------------------------------------------------------
__global__ __launch_bounds__(256)
void wprep_kernel(const float* __restrict__ Wq,
                  const float* __restrict__ Wk,
                  const float* __restrict__ Wv,
                  unsigned short* __restrict__ Wt)
{
    int idx = blockIdx.x * 256 + threadIdx.x;
    int k = idx / 192;
    int n = idx - k * 192;
    int sel = n >> 6, nc = n & 63;
    const float* wp = (sel == 0) ? Wq : ((sel == 1) ? Wk : Wv);
    Wt[n * EMBED + k] = bfround(wp[(size_t)k * HEAD + nc]);
}

// ---------------------------------------------------------------------------
// proj v2 (unchanged from R8, measured 7.0 us ~ at HBM floor).
// ---------------------------------------------------------------------------
__global__ __launch_bounds__(512)
void proj_kernel(const float* __restrict__ x,
                 const unsigned short* __restrict__ Wt,
                 unsigned short* __restrict__ Qo,
                 unsigned short* __restrict__ Ko,
                 unsigned short* __restrict__ Vto)
{
    __shared__ __attribute__((aligned(16))) unsigned short ws[2][192][128]; // 96KB
    __shared__ __attribute__((aligned(16))) unsigned short xs[2][64][128];  // 32KB
    unsigned short (*vbuf)[72] = (unsigned short (*)[72])&xs[1][0][0];

    const int t    = threadIdx.x;   // 0..511
    const int lane = t & 63;
    const int w    = t >> 6;        // 0..7
    const int quad = lane >> 4;
    const int l16  = lane & 15;
    const int wr   = w & 3;         // row group (16 rows)
    const int wc   = w >> 2;        // col group (96 cols)
    const int r0   = blockIdx.x * 64;

    const int xr  = t >> 5, xc4 = t & 31;
    const int xch = xc4 >> 1, xsub = (xc4 & 1) * 4;
    const int wrw = t >> 4, wcc = t & 15;

    f32x4 acc[6];
#pragma unroll
    for (int i = 0; i < 6; ++i) acc[i] = (f32x4){0.f, 0.f, 0.f, 0.f};

    float4 xv[4];
    uint4  wv[6];
#pragma unroll
    for (int i = 0; i < 4; ++i)
        xv[i] = *(const float4*)(x + (size_t)(r0 + xr + 16 * i) * EMBED + xc4 * 4);
#pragma unroll
    for (int i = 0; i < 6; ++i)
        wv[i] = *(const uint4*)(Wt + (size_t)(wrw + 32 * i) * EMBED + wcc * 8);

    int cur = 0;
#pragma unroll
    for (int ph = 0; ph < 3; ++ph) {
#pragma unroll
        for (int i = 0; i < 4; ++i) {
            int row = xr + 16 * i;
            uint2 pw; pw.x = packbf(xv[i].x, xv[i].y); pw.y = packbf(xv[i].z, xv[i].w);
            *(uint2*)&xs[cur][row][((xch ^ (row & 15)) << 3) + xsub] = pw;
        }
#pragma unroll
        for (int i = 0; i < 6; ++i) {
            int row = wrw + 32 * i;
            *(uint4*)&ws[cur][row][(wcc ^ (row & 15)) << 3] = wv[i];
        }
        __syncthreads();

        if (ph < 2) {
            const int k0 = (ph + 1) * 128;
#pragma unroll
            for (int i = 0; i < 4; ++i)
                xv[i] = *(const float4*)(x + (size_t)(r0 + xr + 16 * i) * EMBED + k0 + xc4 * 4);
#pragma unroll
            for (int i = 0; i < 6; ++i)
                wv[i] = *(const uint4*)(Wt + (size_t)(wrw + 32 * i) * EMBED + k0 + wcc * 8);
        }

#pragma unroll
        for (int s = 0; s < 4; ++s) {
            bf16x8 a = *(const bf16x8*)&xs[cur][wr * 16 + l16][((s * 4 + quad) ^ l16) << 3];
#pragma unroll
            for (int ng = 0; ng < 6; ++ng) {
                bf16x8 b = *(const bf16x8*)&ws[cur][wc * 96 + ng * 16 + l16][((s * 4 + quad) ^ l16) << 3];
                acc[ng] = __builtin_amdgcn_mfma_f32_16x16x32_bf16(a, b, acc[ng], 0, 0, 0);
            }
        }
        cur ^= 1;
    }
    __syncthreads();

#pragma unroll
    for (int ng = 0; ng < 6; ++ng) {
        int cg = wc * 96 + ng * 16 + l16;
#pragma unroll
        for (int r = 0; r < 4; ++r) {
            int row = r0 + wr * 16 + quad * 4 + r;
            float vv = acc[ng][r];
            if (cg < 64) {
                Qo[(size_t)row * HEAD + cg] = bfround(vv * SCALE_Q);
            } else if (cg < 128) {
                Ko[(size_t)row * HEAD + (cg - 64)] = bfround(vv);
            } else {
                vbuf[cg - 128][wr * 16 + quad * 4 + r] = bfround(vv);
            }
        }
    }
    __syncthreads();
    {
        const int batch = r0 >> 12;
        const int s0 = r0 & (NT - 1);
        const int d = t >> 3, c = t & 7;
        *(uint4*)(Vto + ((size_t)(batch * HEAD + d)) * NT + s0 + c * 8) =
            *(const uint4*)&vbuf[d][c * 8];
    }
}

// ---------------------------------------------------------------------------
// attn v4: 512 blocks x 512 thr. u: batch=u&3, sp=(u>>2)&3, p=u>>4 (0..31).
// Block computes q-blocks mA=63-p then mB=p at split sp -> uniform 16-18
// tiles. Waves: qg=w>>1 (16 q-rows), sh=w&1 (32 s-cols). kt = sp+4j <= m.
// Dbuf K/V, one barrier/tile, prefetch after barrier. Seam: merge A via
// dedicated osc/rsc scratch, write partials, reset o/rs, reload Q(mB).
// nB==0 blocks zero-fill the (sp, mB) partial slot.
// ---------------------------------------------------------------------------
__global__ __launch_bounds__(512, 4)
void attn_kernel(const unsigned short* __restrict__ Qi,
                 const unsigned short* __restrict__ Ki,
                 const unsigned short* __restrict__ Vti,
                 float* __restrict__ opart,
                 float* __restrict__ lpart)
{
    __shared__ __attribute__((aligned(16))) unsigned short Kt[2][64][64]; // 16KB
    __shared__ __attribute__((aligned(16))) unsigned short Vs[2][64][64]; // 16KB
    __shared__ __attribute__((aligned(16))) float osc[64][64];            // 16KB
    __shared__ float rsc[64];

    const int t    = threadIdx.x;   // 0..511
    const int w    = t >> 6;
    const int lane = t & 63;
    const int quad = lane >> 4;
    const int l16  = lane & 15;
    const int qg   = w >> 1;        // q-group: 16 rows
    const int sh   = w & 1;         // s-half: 32 cols

    const int u = blockIdx.x;       // 0..511
    const int batch = u & 3;
    const int sp = (u >> 2) & 3;
    const int p  = u >> 4;          // 0..31
    const int mA = 63 - p;          // >= 32 > sp always
    const int mB = p;
    const int nA = ((mA - sp) >> 2) + 1;
    const int nB = (mB >= sp) ? (((mB - sp) >> 2) + 1) : 0;
    const int jtot = nA + nB;

    const unsigned short* Kbg = Ki  + (size_t)batch * NT * HEAD;
    const unsigned short* Vbg = Vti + (size_t)batch * HEAD * NT;
    const unsigned short* Qb  = Qi  + (size_t)batch * NT * HEAD;

    int mcur = mA;
    int q0 = mA * 64 + qg * 16;
    bf16x8 bq0, bq1;
    {
        const unsigned short* qp = Qb + (size_t)(q0 + l16) * HEAD + quad * 8;
        bq0 = *(const bf16x8*)(qp);
        bq1 = *(const bf16x8*)(qp + 32);
    }

    f32x4 o[4];
#pragma unroll
    for (int i = 0; i < 4; ++i) o[i] = (f32x4){0.f, 0.f, 0.f, 0.f};
    float rs = 0.f;

    // staging: 512 threads, one 16B chunk each of K and V per tile
    const int srow = t >> 3, sc = t & 7;
    const int scc  = sc ^ (srow & 7);      // swizzled chunk
    const int sw   = l16 & 7;              // row-swizzle key for frag reads

    // merge helper: s-half reduce via osc/rsc, write partials for q-block mm.
    // Must be called by ALL threads (contains a barrier).
    auto merge_out = [&](int mm) {
        float r = rs;
        r += __shfl_xor(r, 16, 64);
        r += __shfl_xor(r, 32, 64);
        if (sh == 1) {
#pragma unroll
            for (int nd = 0; nd < 4; ++nd)
#pragma unroll
                for (int rr = 0; rr < 4; ++rr)
                    osc[qg * 16 + quad * 4 + rr][nd * 16 + l16] = o[nd][rr];
            if (quad == 0) rsc[qg * 16 + l16] = r;
        }
        __syncthreads();
        if (sh == 0) {
            const int qq0 = mm * 64 + qg * 16;
            r += rsc[qg * 16 + l16];
            if (quad == 0)
                lpart[(size_t)sp * NROWS + batch * NT + qq0 + l16] = r;
            float* ob = opart + (size_t)sp * NROWS * HEAD;
#pragma unroll
            for (int rr = 0; rr < 4; ++rr) {
                size_t off = (size_t)(batch * NT + qq0 + quad * 4 + rr) * HEAD;
#pragma unroll
                for (int nd = 0; nd < 4; ++nd)
                    ob[off + nd * 16 + l16] =
                        o[nd][rr] + osc[qg * 16 + quad * 4 + rr][nd * 16 + l16];
            }
        }
    };

    uint4 kr, vr;
    {
        kr = *(const uint4*)(Kbg + (size_t)(sp * 64 + srow) * HEAD + sc * 8);
        vr = *(const uint4*)(Vbg + (size_t)srow * NT + sp * 64 + sc * 8);
    }

    int cur = 0;
    for (int j = 0; j < jtot; ++j) {
        const bool phB = (j >= nA);
        const int kt = sp + 4 * (phB ? (j - nA) : j);
        // commit staged regs (safe: buf last read at j-2, barrier at j-1)
        *(uint4*)&Kt[cur][srow][scc * 8] = kr;
        *(uint4*)&Vs[cur][srow][scc * 8] = vr;
        __syncthreads(); // tile visible; j-1 reads complete

        if (j == nA) {
            // seam: phase A done -> merge + write partials, reset, switch Q.
            merge_out(mA);
#pragma unroll
            for (int i = 0; i < 4; ++i) o[i] = (f32x4){0.f, 0.f, 0.f, 0.f};
            rs = 0.f;
            mcur = mB;
            q0 = mB * 64 + qg * 16;
            const unsigned short* qp = Qb + (size_t)(q0 + l16) * HEAD + quad * 8;
            bq0 = *(const bf16x8*)(qp);
            bq1 = *(const bf16x8*)(qp + 32);
        }

        // prefetch next tile AFTER the barrier; hides under this tile's compute
        if (j + 1 < jtot) {
            const int ktn = sp + 4 * ((j + 1 >= nA) ? (j + 1 - nA) : (j + 1));
            kr = *(const uint4*)(Kbg + (size_t)(ktn * 64 + srow) * HEAD + sc * 8);
            vr = *(const uint4*)(Vbg + (size_t)srow * NT + ktn * 64 + sc * 8);
        }

        const bool diag = (kt == mcur);
        uint2 pw[2];
#pragma unroll
        for (int tsl = 0; tsl < 2; ++tsl) {
            const int ts = sh * 2 + tsl;
            bf16x8 ak0 = *(const bf16x8*)&Kt[cur][ts * 16 + l16][(quad ^ sw) * 8];
            bf16x8 ak1 = *(const bf16x8*)&Kt[cur][ts * 16 + l16][((4 + quad) ^ sw) * 8];
            f32x4 z = (f32x4){0.f, 0.f, 0.f, 0.f};
            z = __builtin_amdgcn_mfma_f32_16x16x32_bf16(ak0, bq0, z, 0, 0, 0);
            z = __builtin_amdgcn_mfma_f32_16x16x32_bf16(ak1, bq1, z, 0, 0, 0);
            // z[r] = S^T[s = kt*64+ts*16+quad*4+r][q = q0+l16], exp2 domain
            float pq[4];
#pragma unroll
            for (int r = 0; r < 4; ++r) {
                float pv = __builtin_amdgcn_exp2f(z[r]);
                if (diag) {
                    int sg = kt * 64 + ts * 16 + quad * 4 + r;
                    pv = (sg > q0 + l16) ? 0.f : pv;
                }
                pq[r] = pv;
            }
            rs += (pq[0] + pq[1]) + (pq[2] + pq[3]);
            pw[tsl].x = cvtpk(pq[0], pq[1]);
            pw[tsl].y = cvtpk(pq[2], pq[3]);
        }

        // In-register C->A transform for this wave's 32-s half.
        unsigned a0 = pw[0].x, c0 = pw[0].y, b0 = pw[1].x, d0 = pw[1].y;
        pl_swap32(a0, b0); pl_swap32(c0, d0);
        pl_swap16(a0, b0); pl_swap16(c0, d0);
        union { unsigned uu[4]; bf16x8 v; } ua;
        ua.uu[0] = a0; ua.uu[1] = c0; ua.uu[2] = b0; ua.uu[3] = d0;
        const bf16x8 ap = ua.v;

        // PV over this s-half
#pragma unroll
        for (int nd = 0; nd < 4; ++nd) {
            bf16x8 av = *(const bf16x8*)&Vs[cur][nd * 16 + l16][((4 * sh + quad) ^ sw) * 8];
            o[nd] = __builtin_amdgcn_mfma_f32_16x16x32_bf16(ap, av, o[nd], 0, 0, 0);
        }
        cur ^= 1;
    }

    // final merge: phase B if it ran, else phase A.
    merge_out(nB > 0 ? mB : mA);

    if (nB == 0 && sh == 0) {
        // phase-B rows never computed at this sp: zero-fill the partial slot.
        const int qq0 = mB * 64 + qg * 16;
        if (quad == 0)
            lpart[(size_t)sp * NROWS + batch * NT + qq0 + l16] = 0.f;
        float* ob = opart + (size_t)sp * NROWS * HEAD;
#pragma unroll
        for (int rr = 0; rr < 4; ++rr) {
            size_t off = (size_t)(batch * NT + qq0 + quad * 4 + rr) * HEAD;
#pragma unroll
            for (int nd = 0; nd < 4; ++nd)
                ob[off + nd * 16 + l16] = 0.f;
        }
    }
}

// ---------------------------------------------------------------------------
// combine: out = sum_sp(o_sp) / sum_sp(l_sp), one float4 per thread.
// ---------------------------------------------------------------------------
__global__ __launch_bounds__(256)
void combine_kernel(const float* __restrict__ opart,
                    const float* __restrict__ lpart,
                    float* __restrict__ out)
{
    int gid = blockIdx.x * 256 + threadIdx.x;   // 0 .. NROWS*16-1
    int row = gid >> 4;
    int d4  = (gid & 15) * 4;
    const size_t st = (size_t)NROWS * HEAD;
    const float* p0 = opart + (size_t)row * HEAD + d4;
    f32x4 a = *(const f32x4*)(p0);
    f32x4 b = *(const f32x4*)(p0 + st);
    f32x4 c = *(const f32x4*)(p0 + 2 * st);
    f32x4 d = *(const f32x4*)(p0 + 3 * st);
    float inv = 1.0f / (lpart[row] + lpart[NROWS + row] +
                        lpart[2 * NROWS + row] + lpart[3 * NROWS + row]);
    f32x4 res = (a + b) + (c + d);
    res[0] *= inv; res[1] *= inv; res[2] *= inv; res[3] *= inv;
    *(f32x4*)(out + (size_t)row * HEAD + d4) = res;
}

extern "C" void kernel_launch(void* const* d_in, const int* in_sizes, int n_in,
                              void* d_out, int out_size, void* d_ws, size_t ws_size,
                              hipStream_t stream)
{
    const float* x  = (const float*)d_in[0];
    const float* Wq = (const float*)d_in[1];
    const float* Wk = (const float*)d_in[2];
    const float* Wv = (const float*)d_in[3];
    float* out = (float*)d_out;

    // ws: Q | K | V^T (bf16, 2MB each) | W^T (144KB) | opart (16MB) | lpart (256KB)
    unsigned short* Qw  = (unsigned short*)d_ws;
    unsigned short* Kw  = Qw + (size_t)NROWS * HEAD;
    unsigned short* Vtw = Kw + (size_t)NROWS * HEAD;
    unsigned short* Wtw = Vtw + (size_t)NROWS * HEAD;
    float* opart = (float*)(Wtw + (size_t)192 * EMBED);
    float* lpart = opart + (size_t)NSPLIT * NROWS * HEAD;

    wprep_kernel<<<(192 * EMBED) / 256, 256, 0, stream>>>(Wq, Wk, Wv, Wtw);
    proj_kernel<<<256, 512, 0, stream>>>(x, Wtw, Qw, Kw, Vtw);
    attn_kernel<<<512, 512, 0, stream>>>(Qw, Kw, Vtw, opart, lpart);
    combine_kernel<<<NROWS * 16 / 256, 256, 0, stream>>>(opart, lpart, out);
}

// Round 8
// 104.790 us; speedup vs baseline: 1.0365x; 1.0365x over previous
//
#include <hip/hip_runtime.h>
#include <hip/hip_bf16.h>
#include <stdint.h>

// Fused causal attention head, MI355X (gfx950). Round 12.
// attn v5: same grid/schedule as v3 (1024x256, 4 blk/CU, LPT, dbuf K/V,
// one barrier/tile, prefetch-after-barrier) but 32x32x16 MFMAs: 4 waves of
// 32q x 32s (qg x sh). Per wave per tile: 4 QK MFMA (d-chunks) + 4 PV MFMA,
// K/V frag reads have zero intra-wave redundancy -> LDS traffic per
// tile-block 80KB -> 48KB (the R11 post-mortem says attn is LDS-port bound).
// P C->B-frag transform: 8 cvt_pk + 4 permlane32_swap (derivation in code).
// End merge: s-halves summed via osc overlay on retired KV LDS ([64][65]
// pad), then cooperative float4-coalesced opart write.
// wprep/proj/combine identical to R10/R11.

#define EMBED 384
#define HEAD  64
#define NB    4
#define NT    4096
#define NROWS (NB * NT) // 16384
#define NSPLIT 4

#define SCALE_Q 0.18033688011112042f // 0.125 * log2(e), folded into Q

typedef short bf16x8 __attribute__((ext_vector_type(8)));
typedef float f32x4  __attribute__((ext_vector_type(4)));
typedef float f32x16 __attribute__((ext_vector_type(16)));

__device__ __forceinline__ unsigned short bfround(float f) {
    union { float f; unsigned u; } v; v.f = f;
    return (unsigned short)((v.u + 0x8000u) >> 16);
}
__device__ __forceinline__ unsigned packbf(float lo, float hi) {
    union { float f; unsigned u; } a, b; a.f = lo; b.f = hi;
    return ((a.u + 0x8000u) >> 16) | ((b.u + 0x8000u) & 0xFFFF0000u);
}
__device__ __forceinline__ unsigned cvtpk(float lo, float hi) {
    unsigned r;
    asm("v_cvt_pk_bf16_f32 %0, %1, %2" : "=v"(r) : "v"(lo), "v"(hi));
    return r;
}
// permlane32_swap: a's upper-32-lane values <-> b's lower-32-lane values.
__device__ __forceinline__ void pl_swap32(unsigned& a, unsigned& b) {
    asm("v_permlane32_swap_b32 %0, %1" : "+v"(a), "+v"(b));
}

// ---------------------------------------------------------------------------
__global__ __launch_bounds__(256)
void wprep_kernel(const float* __restrict__ Wq,
                  const float* __restrict__ Wk,
                  const float* __restrict__ Wv,
                  unsigned short* __restrict__ Wt)
{
    int idx = blockIdx.x * 256 + threadIdx.x;
    int k = idx / 192;
    int n = idx - k * 192;
    int sel = n >> 6, nc = n & 63;
    const float* wp = (sel == 0) ? Wq : ((sel == 1) ? Wk : Wv);
    Wt[n * EMBED + k] = bfround(wp[(size_t)k * HEAD + nc]);
}

// ---------------------------------------------------------------------------
// proj v2 (unchanged from R8, measured 7.0 us ~ at HBM floor).
// ---------------------------------------------------------------------------
__global__ __launch_bounds__(512)
void proj_kernel(const float* __restrict__ x,
                 const unsigned short* __restrict__ Wt,
                 unsigned short* __restrict__ Qo,
                 unsigned short* __restrict__ Ko,
                 unsigned short* __restrict__ Vto)
{
    __shared__ __attribute__((aligned(16))) unsigned short ws[2][192][128]; // 96KB
    __shared__ __attribute__((aligned(16))) unsigned short xs[2][64][128];  // 32KB
    unsigned short (*vbuf)[72] = (unsigned short (*)[72])&xs[1][0][0];

    const int t    = threadIdx.x;   // 0..511
    const int lane = t & 63;
    const int w    = t >> 6;        // 0..7
    const int quad = lane >> 4;
    const int l16  = lane & 15;
    const int wr   = w & 3;         // row group (16 rows)
    const int wc   = w >> 2;        // col group (96 cols)
    const int r0   = blockIdx.x * 64;

    const int xr  = t >> 5, xc4 = t & 31;
    const int xch = xc4 >> 1, xsub = (xc4 & 1) * 4;
    const int wrw = t >> 4, wcc = t & 15;

    f32x4 acc[6];
#pragma unroll
    for (int i = 0; i < 6; ++i) acc[i] = (f32x4){0.f, 0.f, 0.f, 0.f};

    float4 xv[4];
    uint4  wv[6];
#pragma unroll
    for (int i = 0; i < 4; ++i)
        xv[i] = *(const float4*)(x + (size_t)(r0 + xr + 16 * i) * EMBED + xc4 * 4);
#pragma unroll
    for (int i = 0; i < 6; ++i)
        wv[i] = *(const uint4*)(Wt + (size_t)(wrw + 32 * i) * EMBED + wcc * 8);

    int cur = 0;
#pragma unroll
    for (int ph = 0; ph < 3; ++ph) {
#pragma unroll
        for (int i = 0; i < 4; ++i) {
            int row = xr + 16 * i;
            uint2 pw; pw.x = packbf(xv[i].x, xv[i].y); pw.y = packbf(xv[i].z, xv[i].w);
            *(uint2*)&xs[cur][row][((xch ^ (row & 15)) << 3) + xsub] = pw;
        }
#pragma unroll
        for (int i = 0; i < 6; ++i) {
            int row = wrw + 32 * i;
            *(uint4*)&ws[cur][row][(wcc ^ (row & 15)) << 3] = wv[i];
        }
        __syncthreads();

        if (ph < 2) {
            const int k0 = (ph + 1) * 128;
#pragma unroll
            for (int i = 0; i < 4; ++i)
                xv[i] = *(const float4*)(x + (size_t)(r0 + xr + 16 * i) * EMBED + k0 + xc4 * 4);
#pragma unroll
            for (int i = 0; i < 6; ++i)
                wv[i] = *(const uint4*)(Wt + (size_t)(wrw + 32 * i) * EMBED + k0 + wcc * 8);
        }

#pragma unroll
        for (int s = 0; s < 4; ++s) {
            bf16x8 a = *(const bf16x8*)&xs[cur][wr * 16 + l16][((s * 4 + quad) ^ l16) << 3];
#pragma unroll
            for (int ng = 0; ng < 6; ++ng) {
                bf16x8 b = *(const bf16x8*)&ws[cur][wc * 96 + ng * 16 + l16][((s * 4 + quad) ^ l16) << 3];
                acc[ng] = __builtin_amdgcn_mfma_f32_16x16x32_bf16(a, b, acc[ng], 0, 0, 0);
            }
        }
        cur ^= 1;
    }
    __syncthreads();

#pragma unroll
    for (int ng = 0; ng < 6; ++ng) {
        int cg = wc * 96 + ng * 16 + l16;
#pragma unroll
        for (int r = 0; r < 4; ++r) {
            int row = r0 + wr * 16 + quad * 4 + r;
            float vv = acc[ng][r];
            if (cg < 64) {
                Qo[(size_t)row * HEAD + cg] = bfround(vv * SCALE_Q);
            } else if (cg < 128) {
                Ko[(size_t)row * HEAD + (cg - 64)] = bfround(vv);
            } else {
                vbuf[cg - 128][wr * 16 + quad * 4 + r] = bfround(vv);
            }
        }
    }
    __syncthreads();
    {
        const int batch = r0 >> 12;
        const int s0 = r0 & (NT - 1);
        const int d = t >> 3, c = t & 7;
        *(uint4*)(Vto + ((size_t)(batch * HEAD + d)) * NT + s0 + c * 8) =
            *(const uint4*)&vbuf[d][c * 8];
    }
}

// ---------------------------------------------------------------------------
// attn v5: 1024 blocks x 256 thr. Mapping identical to v3: g=u>>4,
// m = g<32 ? 63-g : g-32, sp=(u>>2)&3, batch=u&3, kt = sp+4j <= m.
// 4 waves: qg=w>>1 (32 q-rows), sh=w&1 (32 s-cols). 32x32x16 MFMAs.
// Frag layouts: A/B row(col)=l&31, k=(l>>5)*8+j. C/D: col=l&31,
// row=(reg&3)+8*(reg>>2)+4*(l>>5).
// QK: z = sum_dc mfma(K[32s][16d], Q[32q][16d]) -> z[r]=S^T[s][q].
// P->B-frag (B[q][k=s]): lane already has col=q; need s = sk*16+hi*8+j.
//   x0..x7 = cvtpk(p2k,p2k+1): xk holds s {2k,2k+1}+4hi (k<4: s<16; k>=4: +16)
//   swap32(x0,x2),swap32(x1,x3): bp0=(x0,x1,x2,x3)  [s 0..15]
//   swap32(x4,x6),swap32(x5,x7): bp1=(x4,x5,x6,x7)  [s 16..31]
// PV: o[dg] += mfma(V^T[32d][16s], bp[sk]) -> o[r]=O^T[d][q].
// End merge: osc[64][65] f32 overlay on retired KV; sh=1 writes, sh=0
// adds + lpart; coop transpose -> coalesced opart float4 writes.
// ---------------------------------------------------------------------------
__global__ __launch_bounds__(256, 4)
void attn_kernel(const unsigned short* __restrict__ Qi,
                 const unsigned short* __restrict__ Ki,
                 const unsigned short* __restrict__ Vti,
                 float* __restrict__ opart,
                 float* __restrict__ lpart)
{
    // KV[buf][0] = K tile [64s][64d], KV[buf][1] = V^T tile [64d][64s]. 32KB.
    __shared__ __attribute__((aligned(16))) unsigned short KV[2][2][64][64];
    __shared__ float rsc[64];

    const int t    = threadIdx.x;   // 0..255
    const int w    = t >> 6;        // 0..3
    const int lane = t & 63;
    const int l32  = lane & 31;
    const int hi   = lane >> 5;
    const int qg   = w >> 1;        // 32-q group
    const int sh   = w & 1;         // 32-s half

    const int u = blockIdx.x;
    const int g = u >> 4;
    const int m = (g < 32) ? (63 - g) : (g - 32);
    const int sp = (u >> 2) & 3;
    const int batch = u & 3;
    const int ntiles = (m >= sp) ? (((m - sp) >> 2) + 1) : 0;
    const int q0w = m * 64 + qg * 32;

    const unsigned short* Kbg = Ki  + (size_t)batch * NT * HEAD;
    const unsigned short* Vbg = Vti + (size_t)batch * HEAD * NT;

    // Q B-frags: bq[dc] = Q[q0w + l32][dc*16 + hi*8 + j] (Q carries scale)
    bf16x8 bq[4];
#pragma unroll
    for (int dc = 0; dc < 4; ++dc)
        bq[dc] = *(const bf16x8*)(Qi + (size_t)(batch * NT + q0w + l32) * HEAD
                                  + dc * 16 + hi * 8);

    f32x16 o0, o1;
#pragma unroll
    for (int i = 0; i < 16; ++i) { o0[i] = 0.f; o1[i] = 0.f; }
    float rs = 0.f;

    // staging (v2-proven indices): 2 K chunks + 2 V chunks per thread
    const int srow0 = t >> 3, sc = t & 7;  // rows 0..31
    const int srow1 = srow0 + 32;          // rows 32..63
    const int scc0 = sc ^ (srow0 & 7);
    const int scc1 = sc ^ (srow1 & 7);
    const int r7 = l32 & 7;                // frag-read swizzle key

    uint4 kr0, kr1, vr0, vr1;
    if (ntiles > 0) {
        kr0 = *(const uint4*)(Kbg + (size_t)(sp * 64 + srow0) * HEAD + sc * 8);
        kr1 = *(const uint4*)(Kbg + (size_t)(sp * 64 + srow1) * HEAD + sc * 8);
        vr0 = *(const uint4*)(Vbg + (size_t)srow0 * NT + sp * 64 + sc * 8);
        vr1 = *(const uint4*)(Vbg + (size_t)srow1 * NT + sp * 64 + sc * 8);
    }

    int cur = 0;
    for (int j = 0; j < ntiles; ++j) {
        const int kt = sp + 4 * j;
        *(uint4*)&KV[cur][0][srow0][scc0 * 8] = kr0;
        *(uint4*)&KV[cur][0][srow1][scc1 * 8] = kr1;
        *(uint4*)&KV[cur][1][srow0][scc0 * 8] = vr0;
        *(uint4*)&KV[cur][1][srow1][scc1 * 8] = vr1;
        __syncthreads(); // tile visible; j-1 reads complete

        if (j + 1 < ntiles) {
            const int ktn = kt + 4;
            kr0 = *(const uint4*)(Kbg + (size_t)(ktn * 64 + srow0) * HEAD + sc * 8);
            kr1 = *(const uint4*)(Kbg + (size_t)(ktn * 64 + srow1) * HEAD + sc * 8);
            vr0 = *(const uint4*)(Vbg + (size_t)srow0 * NT + ktn * 64 + sc * 8);
            vr1 = *(const uint4*)(Vbg + (size_t)srow1 * NT + ktn * 64 + sc * 8);
        }

        // ---- QK^T over this wave's 32s x 32q ----
        f32x16 z;
#pragma unroll
        for (int i = 0; i < 16; ++i) z[i] = 0.f;
        const unsigned short* kb = &KV[cur][0][sh * 32 + l32][0];
#pragma unroll
        for (int dc = 0; dc < 4; ++dc) {
            bf16x8 ak = *(const bf16x8*)&kb[(((dc << 1) | hi) ^ r7) << 3];
            z = __builtin_amdgcn_mfma_f32_32x32x16_bf16(ak, bq[dc], z, 0, 0, 0);
        }

        // ---- exp2 + causal mask + row-sum + pack ----
        const bool diag = (kt == m);
        const int qglob = q0w + l32;
        float pq[16];
#pragma unroll
        for (int r = 0; r < 16; ++r) {
            float pv = __builtin_amdgcn_exp2f(z[r]);
            if (diag) {
                int sg = kt * 64 + sh * 32 + (r & 3) + 8 * (r >> 2) + 4 * hi;
                pv = (sg > qglob) ? 0.f : pv;
            }
            pq[r] = pv;
        }
        rs += (((pq[0] + pq[1]) + (pq[2] + pq[3])) + ((pq[4] + pq[5]) + (pq[6] + pq[7])))
            + (((pq[8] + pq[9]) + (pq[10] + pq[11])) + ((pq[12] + pq[13]) + (pq[14] + pq[15])));

        unsigned x0 = cvtpk(pq[0], pq[1]),  x1 = cvtpk(pq[2], pq[3]);
        unsigned x2 = cvtpk(pq[4], pq[5]),  x3 = cvtpk(pq[6], pq[7]);
        unsigned x4 = cvtpk(pq[8], pq[9]),  x5 = cvtpk(pq[10], pq[11]);
        unsigned x6 = cvtpk(pq[12], pq[13]), x7 = cvtpk(pq[14], pq[15]);
        pl_swap32(x0, x2); pl_swap32(x1, x3);
        pl_swap32(x4, x6); pl_swap32(x5, x7);
        union { unsigned uu[4]; bf16x8 v; } b0, b1;
        b0.uu[0] = x0; b0.uu[1] = x1; b0.uu[2] = x2; b0.uu[3] = x3;
        b1.uu[0] = x4; b1.uu[1] = x5; b1.uu[2] = x6; b1.uu[3] = x7;

        // ---- PV over this s-half ----
        const unsigned short* vb0 = &KV[cur][1][l32][0];
        const unsigned short* vb1 = &KV[cur][1][32 + l32][0];
#pragma unroll
        for (int sk = 0; sk < 2; ++sk) {
            const int c = sh * 4 + sk * 2 + hi;
            bf16x8 av0 = *(const bf16x8*)&vb0[((c ^ r7) << 3)];
            bf16x8 av1 = *(const bf16x8*)&vb1[((c ^ r7) << 3)];
            const bf16x8 bp = sk ? b1.v : b0.v;
            o0 = __builtin_amdgcn_mfma_f32_32x32x16_bf16(av0, bp, o0, 0, 0, 0);
            o1 = __builtin_amdgcn_mfma_f32_32x32x16_bf16(av1, bp, o1, 0, 0, 0);
        }
        cur ^= 1;
    }

    // ---- end merge across s-halves ----
    float rs2 = rs + __shfl_xor(rs, 32, 64); // full 32s sum for q = q0w+l32
    __syncthreads(); // retire KV; reuse as osc
    float (*osc)[65] = (float (*)[65])&KV[0][0][0][0]; // [64][65] f32 = 16.6KB
    if (sh == 1) {
#pragma unroll
        for (int r = 0; r < 16; ++r) {
            osc[(r & 3) + 8 * (r >> 2) + 4 * hi][qg * 32 + l32] = o0[r];
            osc[32 + (r & 3) + 8 * (r >> 2) + 4 * hi][qg * 32 + l32] = o1[r];
        }
        if (lane < 32) rsc[qg * 32 + l32] = rs2;
    }
    __syncthreads();
    if (sh == 0) {
#pragma unroll
        for (int r = 0; r < 16; ++r) {
            osc[(r & 3) + 8 * (r >> 2) + 4 * hi][qg * 32 + l32] += o0[r];
            osc[32 + (r & 3) + 8 * (r >> 2) + 4 * hi][qg * 32 + l32] += o1[r];
        }
        if (lane < 32) {
            float rtot = rs2 + rsc[qg * 32 + l32];
            lpart[(size_t)sp * NROWS + batch * NT + m * 64 + qg * 32 + l32] = rtot;
        }
    }
    __syncthreads();
    // cooperative coalesced opart write: lanes 0..15 cover one q-row (256B)
    {
        float* ob = opart + (size_t)sp * NROWS * HEAD
                  + (size_t)(batch * NT + m * 64) * HEAD;
        const int d0 = (t & 15) * 4;
#pragma unroll
        for (int i = 0; i < 4; ++i) {
            const int q = i * 16 + (t >> 4);
            f32x4 v;
            v[0] = osc[d0 + 0][q]; v[1] = osc[d0 + 1][q];
            v[2] = osc[d0 + 2][q]; v[3] = osc[d0 + 3][q];
            *(f32x4*)&ob[(size_t)q * HEAD + d0] = v;
        }
    }
}

// ---------------------------------------------------------------------------
// combine: out = sum_sp(o_sp) / sum_sp(l_sp), one float4 per thread.
// ---------------------------------------------------------------------------
__global__ __launch_bounds__(256)
void combine_kernel(const float* __restrict__ opart,
                    const float* __restrict__ lpart,
                    float* __restrict__ out)
{
    int gid = blockIdx.x * 256 + threadIdx.x;   // 0 .. NROWS*16-1
    int row = gid >> 4;
    int d4  = (gid & 15) * 4;
    const size_t st = (size_t)NROWS * HEAD;
    const float* p0 = opart + (size_t)row * HEAD + d4;
    f32x4 a = *(const f32x4*)(p0);
    f32x4 b = *(const f32x4*)(p0 + st);
    f32x4 c = *(const f32x4*)(p0 + 2 * st);
    f32x4 d = *(const f32x4*)(p0 + 3 * st);
    float inv = 1.0f / (lpart[row] + lpart[NROWS + row] +
                        lpart[2 * NROWS + row] + lpart[3 * NROWS + row]);
    f32x4 res = (a + b) + (c + d);
    res[0] *= inv; res[1] *= inv; res[2] *= inv; res[3] *= inv;
    *(f32x4*)(out + (size_t)row * HEAD + d4) = res;
}

extern "C" void kernel_launch(void* const* d_in, const int* in_sizes, int n_in,
                              void* d_out, int out_size, void* d_ws, size_t ws_size,
                              hipStream_t stream)
{
    const float* x  = (const float*)d_in[0];
    const float* Wq = (const float*)d_in[1];
    const float* Wk = (const float*)d_in[2];
    const float* Wv = (const float*)d_in[3];
    float* out = (float*)d_out;

    // ws: Q | K | V^T (bf16, 2MB each) | W^T (144KB) | opart (16MB) | lpart (256KB)
    unsigned short* Qw  = (unsigned short*)d_ws;
    unsigned short* Kw  = Qw + (size_t)NROWS * HEAD;
    unsigned short* Vtw = Kw + (size_t)NROWS * HEAD;
    unsigned short* Wtw = Vtw + (size_t)NROWS * HEAD;
    float* opart = (float*)(Wtw + (size_t)192 * EMBED);
    float* lpart = opart + (size_t)NSPLIT * NROWS * HEAD;

    wprep_kernel<<<(192 * EMBED) / 256, 256, 0, stream>>>(Wq, Wk, Wv, Wtw);
    proj_kernel<<<256, 512, 0, stream>>>(x, Wtw, Qw, Kw, Vtw);
    attn_kernel<<<1024, 256, 0, stream>>>(Qw, Kw, Vtw, opart, lpart);
    combine_kernel<<<NROWS * 16 / 256, 256, 0, stream>>>(opart, lpart, out);
}